// Round 1
// baseline (11692.205 us; speedup 1.0000x reference)
//
#include <hip/hip_runtime.h>
#include <hip/hip_bf16.h>
#include <math.h>

#define D_MODEL 768
#define NUM_HEADS 12
#define D_K 64
#define SEQ 2048
#define BATCH 4
#define QKV_N (3 * D_MODEL)   // 2304

// ---------------------------------------------------------------------------
// Tiled fp32 GEMM with fused bias: C[M,N] = A[M,K] @ B[K,N] + bias[N]
// BM=BN=64, BK=16, 256 threads, each thread computes a 4x4 micro-tile.
// All dims here are multiples of the tile sizes (M=8192, N in {2304,768}, K=768).
// ---------------------------------------------------------------------------
__global__ __launch_bounds__(256) void gemm_bias_kernel(
    const float* __restrict__ A, const float* __restrict__ B,
    const float* __restrict__ bias, float* __restrict__ C,
    int M, int N, int K) {
  const int bm = blockIdx.y * 64;
  const int bn = blockIdx.x * 64;
  const int tid = threadIdx.x;
  const int ty = tid >> 4;   // 0..15
  const int tx = tid & 15;   // 0..15

  __shared__ float As[16][65];  // [k][m], +1 pad
  __shared__ float Bs[16][65];  // [k][n], +1 pad

  float acc[4][4];
#pragma unroll
  for (int i = 0; i < 4; ++i)
#pragma unroll
    for (int j = 0; j < 4; ++j) acc[i][j] = 0.f;

  for (int k0 = 0; k0 < K; k0 += 16) {
    // load A tile: rows bm..bm+63, cols k0..k0+15  (64*16 = 1024 elems, 4/thread)
#pragma unroll
    for (int i = 0; i < 4; ++i) {
      int idx = tid + i * 256;
      int r = idx >> 4;        // 0..63
      int c = idx & 15;        // 0..15
      As[c][r] = A[(size_t)(bm + r) * K + (k0 + c)];
    }
    // load B tile: rows k0..k0+15, cols bn..bn+63
#pragma unroll
    for (int i = 0; i < 4; ++i) {
      int idx = tid + i * 256;
      int r = idx >> 6;        // 0..15
      int c = idx & 63;        // 0..63
      Bs[r][c] = B[(size_t)(k0 + r) * N + (bn + c)];
    }
    __syncthreads();

#pragma unroll
    for (int kk = 0; kk < 16; ++kk) {
      float a[4], b[4];
#pragma unroll
      for (int i = 0; i < 4; ++i) a[i] = As[kk][ty * 4 + i];
#pragma unroll
      for (int j = 0; j < 4; ++j) b[j] = Bs[kk][tx * 4 + j];
#pragma unroll
      for (int i = 0; i < 4; ++i)
#pragma unroll
        for (int j = 0; j < 4; ++j) acc[i][j] += a[i] * b[j];
    }
    __syncthreads();
  }

#pragma unroll
  for (int i = 0; i < 4; ++i) {
    int row = bm + ty * 4 + i;
#pragma unroll
    for (int j = 0; j < 4; ++j) {
      int col = bn + tx * 4 + j;
      C[(size_t)row * N + col] = acc[i][j] + bias[col];
    }
  }
}

// ---------------------------------------------------------------------------
// Attention: one block (256 threads) per (b, h, q-row).
// qkv layout per token row (2304 floats): head h -> [h*192 .. h*192+191],
// within that: q = +0..63, k = +64..127, v = +128..191.
// Writes ctx[b, s, h*64 + d]  (i.e. the already-merged [B,S,768] layout).
// ---------------------------------------------------------------------------
__global__ __launch_bounds__(256) void attn_kernel(
    const float* __restrict__ qkv, float* __restrict__ ctx) {
  const int q = blockIdx.x;
  const int h = blockIdx.y;
  const int b = blockIdx.z;
  const int tid = threadIdx.x;

  const float* qkv_b = qkv + (size_t)b * SEQ * QKV_N;
  const float* qrow = qkv_b + (size_t)q * QKV_N + h * (3 * D_K);

  __shared__ float sq[D_K];
  __shared__ float sc[SEQ];     // 8 KB of scores
  __shared__ float red[256];
  __shared__ float pacc[4][D_K];

  if (tid < D_K) sq[tid] = qrow[tid];
  __syncthreads();

  const float scale = 0.125f;  // 1/sqrt(64)

  // scores: each thread handles 8 keys (stride 256)
  for (int k = tid; k < SEQ; k += 256) {
    const float* krow = qkv_b + (size_t)k * QKV_N + h * (3 * D_K) + D_K;
    float acc = 0.f;
#pragma unroll
    for (int d = 0; d < D_K; ++d) acc += sq[d] * krow[d];
    sc[k] = acc * scale;
  }
  __syncthreads();

  // row max
  float lm = -INFINITY;
  for (int k = tid; k < SEQ; k += 256) lm = fmaxf(lm, sc[k]);
  red[tid] = lm;
  __syncthreads();
  for (int s = 128; s > 0; s >>= 1) {
    if (tid < s) red[tid] = fmaxf(red[tid], red[tid + s]);
    __syncthreads();
  }
  const float m = red[0];
  __syncthreads();

  // exp + sum
  float ls = 0.f;
  for (int k = tid; k < SEQ; k += 256) {
    float e = __expf(sc[k] - m);
    sc[k] = e;
    ls += e;
  }
  red[tid] = ls;
  __syncthreads();
  for (int s = 128; s > 0; s >>= 1) {
    if (tid < s) red[tid] += red[tid + s];
    __syncthreads();
  }
  const float denom = red[0];
  __syncthreads();

  // PV: thread (g = tid>>6, d = tid&63); each g-group covers keys g, g+4, ...
  const int d = tid & 63;
  const int g = tid >> 6;
  float acc = 0.f;
  for (int k = g; k < SEQ; k += 4) {
    const float* vrow = qkv_b + (size_t)k * QKV_N + h * (3 * D_K) + 2 * D_K;
    acc += sc[k] * vrow[d];
  }
  pacc[g][d] = acc;
  __syncthreads();

  if (tid < D_K) {
    float r = (pacc[0][tid] + pacc[1][tid] + pacc[2][tid] + pacc[3][tid]) / denom;
    ctx[((size_t)b * SEQ + q) * D_MODEL + h * D_K + tid] = r;
  }
}

// ---------------------------------------------------------------------------
extern "C" void kernel_launch(void* const* d_in, const int* in_sizes, int n_in,
                              void* d_out, int out_size, void* d_ws, size_t ws_size,
                              hipStream_t stream) {
  const float* x     = (const float*)d_in[0];  // [4,2048,768]
  const float* W_qkv = (const float*)d_in[1];  // [768,2304]
  const float* b_qkv = (const float*)d_in[2];  // [2304]
  const float* W_out = (const float*)d_in[3];  // [768,768]
  const float* b_out = (const float*)d_in[4];  // [768]
  float* out = (float*)d_out;                  // [4,2048,768]

  const int M = BATCH * SEQ;  // 8192

  float* qkv = (float*)d_ws;                      // [8192, 2304] = 75.5 MB
  float* ctx = qkv + (size_t)M * QKV_N;           // [8192, 768]  = 25.2 MB

  dim3 block(256);

  // 1) QKV projection: [8192,768] @ [768,2304] + b
  dim3 g1(QKV_N / 64, M / 64);
  hipLaunchKernelGGL(gemm_bias_kernel, g1, block, 0, stream,
                     x, W_qkv, b_qkv, qkv, M, QKV_N, D_MODEL);

  // 2) attention per (b,h,q)
  dim3 g2(SEQ, NUM_HEADS, BATCH);
  hipLaunchKernelGGL(attn_kernel, g2, block, 0, stream, qkv, ctx);

  // 3) output projection: [8192,768] @ [768,768] + b
  dim3 g3(D_MODEL / 64, M / 64);
  hipLaunchKernelGGL(gemm_bias_kernel, g3, block, 0, stream,
                     ctx, W_out, b_out, out, M, D_MODEL, D_MODEL);
}

// Round 6
// 1536.646 us; speedup vs baseline: 7.6089x; 7.6089x over previous
//
#include <hip/hip_runtime.h>
#include <hip/hip_bf16.h>
#include <math.h>

#define D_MODEL 768
#define NUM_HEADS 12
#define D_K 64
#define SEQ 2048
#define BATCH 4
#define QKV_N (3 * D_MODEL)   // 2304

// ---------------------------------------------------------------------------
// Tiled fp32 GEMM with fused bias: C[M,N] = A[M,K] @ B[K,N] + bias[N]
// BM=BN=64, BK=16, 256 threads, each thread computes a 4x4 micro-tile.
// ---------------------------------------------------------------------------
__global__ __launch_bounds__(256) void gemm_bias_kernel(
    const float* __restrict__ A, const float* __restrict__ B,
    const float* __restrict__ bias, float* __restrict__ C,
    int M, int N, int K) {
  const int bm = blockIdx.y * 64;
  const int bn = blockIdx.x * 64;
  const int tid = threadIdx.x;
  const int ty = tid >> 4;   // 0..15
  const int tx = tid & 15;   // 0..15

  __shared__ float As[16][65];  // [k][m], +1 pad
  __shared__ float Bs[16][65];  // [k][n], +1 pad

  float acc[4][4];
#pragma unroll
  for (int i = 0; i < 4; ++i)
#pragma unroll
    for (int j = 0; j < 4; ++j) acc[i][j] = 0.f;

  for (int k0 = 0; k0 < K; k0 += 16) {
#pragma unroll
    for (int i = 0; i < 4; ++i) {
      int idx = tid + i * 256;
      int r = idx >> 4;        // 0..63
      int c = idx & 15;        // 0..15
      As[c][r] = A[(size_t)(bm + r) * K + (k0 + c)];
    }
#pragma unroll
    for (int i = 0; i < 4; ++i) {
      int idx = tid + i * 256;
      int r = idx >> 6;        // 0..15
      int c = idx & 63;        // 0..63
      Bs[r][c] = B[(size_t)(k0 + r) * N + (bn + c)];
    }
    __syncthreads();

#pragma unroll
    for (int kk = 0; kk < 16; ++kk) {
      float a[4], b[4];
#pragma unroll
      for (int i = 0; i < 4; ++i) a[i] = As[kk][ty * 4 + i];
#pragma unroll
      for (int j = 0; j < 4; ++j) b[j] = Bs[kk][tx * 4 + j];
#pragma unroll
      for (int i = 0; i < 4; ++i)
#pragma unroll
        for (int j = 0; j < 4; ++j) acc[i][j] += a[i] * b[j];
    }
    __syncthreads();
  }

#pragma unroll
  for (int i = 0; i < 4; ++i) {
    int row = bm + ty * 4 + i;
#pragma unroll
    for (int j = 0; j < 4; ++j) {
      int col = bn + tx * 4 + j;
      C[(size_t)row * N + col] = acc[i][j] + bias[col];
    }
  }
}

// ---------------------------------------------------------------------------
// Flash-style attention, fp32 vector ALU.
// One block (256 thr = 16x16 thread grid) per (b, h, 64-row q-tile).
// LDS: sQ/sK/sP transposed (inner-dim-major) so all GEMM-phase LDS reads are
// wave-uniform-row broadcasts or full-bank b128 reads (conflict-free).
// Online softmax state (m,l) lives in registers, replicated across the 16
// tx-lanes of each row group; reduced with __shfl_xor (masks 1,2,4,8).
// ---------------------------------------------------------------------------
__global__ __launch_bounds__(256) void flash_attn_kernel(
    const float* __restrict__ qkv, float* __restrict__ ctx) {
  const int qt = blockIdx.x;   // 0..31
  const int h  = blockIdx.y;
  const int b  = blockIdx.z;
  const int tid = threadIdx.x;
  const int tx = tid & 15;
  const int ty = tid >> 4;
  const int q0 = qt * 64;

  __shared__ __align__(16) float sQ[64][68];  // [d][q]
  __shared__ __align__(16) float sK[64][68];  // [d][k]
  __shared__ __align__(16) float sV[64][64];  // [k][d]
  __shared__ __align__(16) float sP[64][68];  // [k][q]

  const float* base = qkv + (size_t)b * (SEQ * QKV_N) + h * (3 * D_K);

  // stage Q tile transposed: sQ[d][q]
  {
    const int d4 = tx * 4;
#pragma unroll
    for (int r = 0; r < 4; ++r) {
      const int qr = ty + 16 * r;
      const float4 v = *(const float4*)(base + (size_t)(q0 + qr) * QKV_N + d4);
      sQ[d4 + 0][qr] = v.x;
      sQ[d4 + 1][qr] = v.y;
      sQ[d4 + 2][qr] = v.z;
      sQ[d4 + 3][qr] = v.w;
    }
  }

  float m_[4], l_[4], o[4][4];
#pragma unroll
  for (int i = 0; i < 4; ++i) {
    m_[i] = -INFINITY;
    l_[i] = 0.f;
#pragma unroll
    for (int j = 0; j < 4; ++j) o[i][j] = 0.f;
  }

  __syncthreads();

  for (int k0 = 0; k0 < SEQ; k0 += 64) {
    // stage K transposed (sK[d][k]) and V natural (sV[k][d])
    {
      const int d4 = tx * 4;
#pragma unroll
      for (int r = 0; r < 4; ++r) {
        const int kr = ty + 16 * r;
        const float* krow = base + (size_t)(k0 + kr) * QKV_N + D_K;
        const float4 kv = *(const float4*)(krow + d4);
        sK[d4 + 0][kr] = kv.x;
        sK[d4 + 1][kr] = kv.y;
        sK[d4 + 2][kr] = kv.z;
        sK[d4 + 3][kr] = kv.w;
        const float* vrow = base + (size_t)(k0 + kr) * QKV_N + 2 * D_K;
        *(float4*)(&sV[kr][d4]) = *(const float4*)(vrow + d4);
      }
    }
    __syncthreads();

    // S = (Q K^T) * scale, 4x4 micro-tile per thread
    float s[4][4];
#pragma unroll
    for (int i = 0; i < 4; ++i)
#pragma unroll
      for (int j = 0; j < 4; ++j) s[i][j] = 0.f;

#pragma unroll 8
    for (int d = 0; d < 64; ++d) {
      const float4 aa = *(const float4*)(&sQ[d][ty * 4]);
      const float4 bb = *(const float4*)(&sK[d][tx * 4]);
      const float av[4] = {aa.x, aa.y, aa.z, aa.w};
      const float bv[4] = {bb.x, bb.y, bb.z, bb.w};
#pragma unroll
      for (int i = 0; i < 4; ++i)
#pragma unroll
        for (int j = 0; j < 4; ++j) s[i][j] += av[i] * bv[j];
    }

    // online softmax update, per q-row (replicated across tx lanes)
#pragma unroll
    for (int i = 0; i < 4; ++i) {
#pragma unroll
      for (int j = 0; j < 4; ++j) s[i][j] *= 0.125f;
      float tm = fmaxf(fmaxf(s[i][0], s[i][1]), fmaxf(s[i][2], s[i][3]));
      tm = fmaxf(tm, __shfl_xor(tm, 1));
      tm = fmaxf(tm, __shfl_xor(tm, 2));
      tm = fmaxf(tm, __shfl_xor(tm, 4));
      tm = fmaxf(tm, __shfl_xor(tm, 8));
      const float mn = fmaxf(m_[i], tm);
      const float sc = __expf(m_[i] - mn);
      m_[i] = mn;
      float rs = 0.f;
#pragma unroll
      for (int j = 0; j < 4; ++j) {
        s[i][j] = __expf(s[i][j] - mn);
        rs += s[i][j];
      }
      rs += __shfl_xor(rs, 1);
      rs += __shfl_xor(rs, 2);
      rs += __shfl_xor(rs, 4);
      rs += __shfl_xor(rs, 8);
      l_[i] = l_[i] * sc + rs;
#pragma unroll
      for (int j = 0; j < 4; ++j) o[i][j] *= sc;
    }

    // write P transposed: sP[k][q]
#pragma unroll
    for (int j = 0; j < 4; ++j) {
      const float4 pv = make_float4(s[0][j], s[1][j], s[2][j], s[3][j]);
      *(float4*)(&sP[tx * 4 + j][ty * 4]) = pv;
    }
    __syncthreads();

    // O += P V, 4x4 micro-tile
#pragma unroll 8
    for (int k = 0; k < 64; ++k) {
      const float4 aa = *(const float4*)(&sP[k][ty * 4]);
      const float4 bb = *(const float4*)(&sV[k][tx * 4]);
      const float av[4] = {aa.x, aa.y, aa.z, aa.w};
      const float bv[4] = {bb.x, bb.y, bb.z, bb.w};
#pragma unroll
      for (int i = 0; i < 4; ++i)
#pragma unroll
        for (int j = 0; j < 4; ++j) o[i][j] += av[i] * bv[j];
    }
    __syncthreads();
  }

  // epilogue: normalize and write ctx[b, q, h*64 + d]
#pragma unroll
  for (int i = 0; i < 4; ++i) {
    const float inv = 1.f / l_[i];
    const float4 r = make_float4(o[i][0] * inv, o[i][1] * inv,
                                 o[i][2] * inv, o[i][3] * inv);
    *(float4*)(ctx + ((size_t)b * SEQ + q0 + ty * 4 + i) * D_MODEL +
               h * D_K + tx * 4) = r;
  }
}

// ---------------------------------------------------------------------------
extern "C" void kernel_launch(void* const* d_in, const int* in_sizes, int n_in,
                              void* d_out, int out_size, void* d_ws, size_t ws_size,
                              hipStream_t stream) {
  const float* x     = (const float*)d_in[0];  // [4,2048,768]
  const float* W_qkv = (const float*)d_in[1];  // [768,2304]
  const float* b_qkv = (const float*)d_in[2];  // [2304]
  const float* W_out = (const float*)d_in[3];  // [768,768]
  const float* b_out = (const float*)d_in[4];  // [768]
  float* out = (float*)d_out;                  // [4,2048,768]

  const int M = BATCH * SEQ;  // 8192

  float* qkv = (float*)d_ws;                   // [8192, 2304]
  float* ctx = qkv + (size_t)M * QKV_N;        // [8192, 768]

  dim3 block(256);

  // 1) QKV projection
  dim3 g1(QKV_N / 64, M / 64);
  hipLaunchKernelGGL(gemm_bias_kernel, g1, block, 0, stream,
                     x, W_qkv, b_qkv, qkv, M, QKV_N, D_MODEL);

  // 2) flash attention
  dim3 g2(SEQ / 64, NUM_HEADS, BATCH);
  hipLaunchKernelGGL(flash_attn_kernel, g2, block, 0, stream, qkv, ctx);

  // 3) output projection
  dim3 g3(D_MODEL / 64, M / 64);
  hipLaunchKernelGGL(gemm_bias_kernel, g3, block, 0, stream,
                     ctx, W_out, b_out, out, M, D_MODEL, D_MODEL);
}

// Round 10
// 1003.634 us; speedup vs baseline: 11.6499x; 1.5311x over previous
//
#include <hip/hip_runtime.h>
#include <hip/hip_bf16.h>
#include <math.h>

#define D_MODEL 768
#define NUM_HEADS 12
#define D_K 64
#define SEQ 2048
#define BATCH 4
#define QKV_N (3 * D_MODEL)   // 2304

typedef _Float16 f16;
typedef f16 f16x4 __attribute__((ext_vector_type(4)));
typedef f16 f16x8 __attribute__((ext_vector_type(8)));
typedef float f32x4 __attribute__((ext_vector_type(4)));

// ---------------------------------------------------------------------------
// fp16 MFMA GEMM with fused bias: C[M,N] = A[M,K] @ B[K,N] + bias[N]
// 128x128 tile, BK=32, 256 threads = 4 waves in 2x2, each wave 64x64 out
// (4x4 grid of 16x16x32 MFMA tiles). A/B staged fp32->fp16 in LDS, [row][k]
// layout padded to 40 f16 (80B stride -> max 2-way conflict on b128 reads).
// M,N,K all multiples of tile dims here (M=8192, N in {2304,768}, K=768).
// ---------------------------------------------------------------------------
__global__ __launch_bounds__(256) void gemm_mfma_f16(
    const float* __restrict__ A, const float* __restrict__ B,
    const float* __restrict__ bias, float* __restrict__ C,
    int M, int N, int K) {
  const int bm = blockIdx.y * 128;
  const int bn = blockIdx.x * 128;
  const int tid = threadIdx.x;
  const int lane = tid & 63;
  const int wave = tid >> 6;
  const int wr = wave >> 1;    // 0..1
  const int wc = wave & 1;     // 0..1

  __shared__ f16 Als[128][40];  // [m][k], pad to 40
  __shared__ f16 Bls[128][40];  // [n][k] (B transposed in staging)

  f32x4 acc[4][4];
#pragma unroll
  for (int i = 0; i < 4; ++i)
#pragma unroll
    for (int j = 0; j < 4; ++j) acc[i][j] = (f32x4){0.f, 0.f, 0.f, 0.f};

  const int frow = lane & 15;        // m (A) / n (B) within 16-tile
  const int ko   = (lane >> 4) * 8;  // k offset of this lane's 8 elements

  for (int k0 = 0; k0 < K; k0 += 32) {
    // stage A tile (128 rows x 32 k): 1024 float4, 4 per thread
#pragma unroll
    for (int i = 0; i < 4; ++i) {
      const int f = tid + i * 256;
      const int r = f >> 3;          // 0..127
      const int c4 = (f & 7) * 4;    // 0..28
      const float4 v = *(const float4*)(A + (size_t)(bm + r) * K + k0 + c4);
      f16x4 h = { (f16)v.x, (f16)v.y, (f16)v.z, (f16)v.w };
      *(f16x4*)(&Als[r][c4]) = h;
    }
    // stage B tile (32 k x 128 n), transposed into Bls[n][k]
#pragma unroll
    for (int i = 0; i < 4; ++i) {
      const int f = tid + i * 256;
      const int kr = f >> 5;          // 0..31
      const int nc4 = (f & 31) * 4;   // 0..124
      const float4 v = *(const float4*)(B + (size_t)(k0 + kr) * N + bn + nc4);
      Bls[nc4 + 0][kr] = (f16)v.x;
      Bls[nc4 + 1][kr] = (f16)v.y;
      Bls[nc4 + 2][kr] = (f16)v.z;
      Bls[nc4 + 3][kr] = (f16)v.w;
    }
    __syncthreads();

    f16x8 af[4], bf[4];
#pragma unroll
    for (int mi = 0; mi < 4; ++mi)
      af[mi] = *(const f16x8*)(&Als[wr * 64 + mi * 16 + frow][ko]);
#pragma unroll
    for (int nj = 0; nj < 4; ++nj)
      bf[nj] = *(const f16x8*)(&Bls[wc * 64 + nj * 16 + frow][ko]);

#pragma unroll
    for (int mi = 0; mi < 4; ++mi)
#pragma unroll
      for (int nj = 0; nj < 4; ++nj)
        acc[mi][nj] = __builtin_amdgcn_mfma_f32_16x16x32_f16(
            af[mi], bf[nj], acc[mi][nj], 0, 0, 0);
    __syncthreads();
  }

  // epilogue: C/D layout col = lane&15, row = (lane>>4)*4 + reg  [HW-verified]
  const int crow = (lane >> 4) * 4;
  const int ccol = lane & 15;
#pragma unroll
  for (int nj = 0; nj < 4; ++nj) {
    const int col = bn + wc * 64 + nj * 16 + ccol;
    const float bv = bias[col];
#pragma unroll
    for (int mi = 0; mi < 4; ++mi) {
      const int rbase = bm + wr * 64 + mi * 16 + crow;
#pragma unroll
      for (int r = 0; r < 4; ++r) {
        C[(size_t)(rbase + r) * N + col] = acc[mi][nj][r] + bv;
      }
    }
  }
}

// ---------------------------------------------------------------------------
// Flash-style attention, fp32 vector ALU (UNCHANGED from round 6).
// ---------------------------------------------------------------------------
__global__ __launch_bounds__(256) void flash_attn_kernel(
    const float* __restrict__ qkv, float* __restrict__ ctx) {
  const int qt = blockIdx.x;   // 0..31
  const int h  = blockIdx.y;
  const int b  = blockIdx.z;
  const int tid = threadIdx.x;
  const int tx = tid & 15;
  const int ty = tid >> 4;
  const int q0 = qt * 64;

  __shared__ __align__(16) float sQ[64][68];  // [d][q]
  __shared__ __align__(16) float sK[64][68];  // [d][k]
  __shared__ __align__(16) float sV[64][64];  // [k][d]
  __shared__ __align__(16) float sP[64][68];  // [k][q]

  const float* base = qkv + (size_t)b * (SEQ * QKV_N) + h * (3 * D_K);

  // stage Q tile transposed: sQ[d][q]
  {
    const int d4 = tx * 4;
#pragma unroll
    for (int r = 0; r < 4; ++r) {
      const int qr = ty + 16 * r;
      const float4 v = *(const float4*)(base + (size_t)(q0 + qr) * QKV_N + d4);
      sQ[d4 + 0][qr] = v.x;
      sQ[d4 + 1][qr] = v.y;
      sQ[d4 + 2][qr] = v.z;
      sQ[d4 + 3][qr] = v.w;
    }
  }

  float m_[4], l_[4], o[4][4];
#pragma unroll
  for (int i = 0; i < 4; ++i) {
    m_[i] = -INFINITY;
    l_[i] = 0.f;
#pragma unroll
    for (int j = 0; j < 4; ++j) o[i][j] = 0.f;
  }

  __syncthreads();

  for (int k0 = 0; k0 < SEQ; k0 += 64) {
    // stage K transposed (sK[d][k]) and V natural (sV[k][d])
    {
      const int d4 = tx * 4;
#pragma unroll
      for (int r = 0; r < 4; ++r) {
        const int kr = ty + 16 * r;
        const float* krow = base + (size_t)(k0 + kr) * QKV_N + D_K;
        const float4 kv = *(const float4*)(krow + d4);
        sK[d4 + 0][kr] = kv.x;
        sK[d4 + 1][kr] = kv.y;
        sK[d4 + 2][kr] = kv.z;
        sK[d4 + 3][kr] = kv.w;
        const float* vrow = base + (size_t)(k0 + kr) * QKV_N + 2 * D_K;
        *(float4*)(&sV[kr][d4]) = *(const float4*)(vrow + d4);
      }
    }
    __syncthreads();

    // S = (Q K^T) * scale, 4x4 micro-tile per thread
    float s[4][4];
#pragma unroll
    for (int i = 0; i < 4; ++i)
#pragma unroll
      for (int j = 0; j < 4; ++j) s[i][j] = 0.f;

#pragma unroll 8
    for (int d = 0; d < 64; ++d) {
      const float4 aa = *(const float4*)(&sQ[d][ty * 4]);
      const float4 bb = *(const float4*)(&sK[d][tx * 4]);
      const float av[4] = {aa.x, aa.y, aa.z, aa.w};
      const float bv[4] = {bb.x, bb.y, bb.z, bb.w};
#pragma unroll
      for (int i = 0; i < 4; ++i)
#pragma unroll
        for (int j = 0; j < 4; ++j) s[i][j] += av[i] * bv[j];
    }

    // online softmax update, per q-row (replicated across tx lanes)
#pragma unroll
    for (int i = 0; i < 4; ++i) {
#pragma unroll
      for (int j = 0; j < 4; ++j) s[i][j] *= 0.125f;
      float tm = fmaxf(fmaxf(s[i][0], s[i][1]), fmaxf(s[i][2], s[i][3]));
      tm = fmaxf(tm, __shfl_xor(tm, 1));
      tm = fmaxf(tm, __shfl_xor(tm, 2));
      tm = fmaxf(tm, __shfl_xor(tm, 4));
      tm = fmaxf(tm, __shfl_xor(tm, 8));
      const float mn = fmaxf(m_[i], tm);
      const float sc = __expf(m_[i] - mn);
      m_[i] = mn;
      float rs = 0.f;
#pragma unroll
      for (int j = 0; j < 4; ++j) {
        s[i][j] = __expf(s[i][j] - mn);
        rs += s[i][j];
      }
      rs += __shfl_xor(rs, 1);
      rs += __shfl_xor(rs, 2);
      rs += __shfl_xor(rs, 4);
      rs += __shfl_xor(rs, 8);
      l_[i] = l_[i] * sc + rs;
#pragma unroll
      for (int j = 0; j < 4; ++j) o[i][j] *= sc;
    }

    // write P transposed: sP[k][q]
#pragma unroll
    for (int j = 0; j < 4; ++j) {
      const float4 pv = make_float4(s[0][j], s[1][j], s[2][j], s[3][j]);
      *(float4*)(&sP[tx * 4 + j][ty * 4]) = pv;
    }
    __syncthreads();

    // O += P V, 4x4 micro-tile
#pragma unroll 8
    for (int k = 0; k < 64; ++k) {
      const float4 aa = *(const float4*)(&sP[k][ty * 4]);
      const float4 bb = *(const float4*)(&sV[k][tx * 4]);
      const float av[4] = {aa.x, aa.y, aa.z, aa.w};
      const float bv[4] = {bb.x, bb.y, bb.z, bb.w};
#pragma unroll
      for (int i = 0; i < 4; ++i)
#pragma unroll
        for (int j = 0; j < 4; ++j) o[i][j] += av[i] * bv[j];
    }
    __syncthreads();
  }

  // epilogue: normalize and write ctx[b, q, h*64 + d]
#pragma unroll
  for (int i = 0; i < 4; ++i) {
    const float inv = 1.f / l_[i];
    const float4 r = make_float4(o[i][0] * inv, o[i][1] * inv,
                                 o[i][2] * inv, o[i][3] * inv);
    *(float4*)(ctx + ((size_t)b * SEQ + q0 + ty * 4 + i) * D_MODEL +
               h * D_K + tx * 4) = r;
  }
}

// ---------------------------------------------------------------------------
extern "C" void kernel_launch(void* const* d_in, const int* in_sizes, int n_in,
                              void* d_out, int out_size, void* d_ws, size_t ws_size,
                              hipStream_t stream) {
  const float* x     = (const float*)d_in[0];  // [4,2048,768]
  const float* W_qkv = (const float*)d_in[1];  // [768,2304]
  const float* b_qkv = (const float*)d_in[2];  // [2304]
  const float* W_out = (const float*)d_in[3];  // [768,768]
  const float* b_out = (const float*)d_in[4];  // [768]
  float* out = (float*)d_out;                  // [4,2048,768]

  const int M = BATCH * SEQ;  // 8192

  float* qkv = (float*)d_ws;                   // [8192, 2304] fp32
  float* ctx = qkv + (size_t)M * QKV_N;        // [8192, 768]  fp32

  dim3 block(256);

  // 1) QKV projection (fp16 MFMA)
  dim3 g1(QKV_N / 128, M / 128);               // (18, 64)
  hipLaunchKernelGGL(gemm_mfma_f16, g1, block, 0, stream,
                     x, W_qkv, b_qkv, qkv, M, QKV_N, D_MODEL);

  // 2) flash attention (fp32, unchanged)
  dim3 g2(SEQ / 64, NUM_HEADS, BATCH);
  hipLaunchKernelGGL(flash_attn_kernel, g2, block, 0, stream, qkv, ctx);

  // 3) output projection (fp16 MFMA)
  dim3 g3(D_MODEL / 128, M / 128);             // (6, 64)
  hipLaunchKernelGGL(gemm_mfma_f16, g3, block, 0, stream,
                     ctx, W_out, b_out, out, M, D_MODEL, D_MODEL);
}

// Round 12
// 334.357 us; speedup vs baseline: 34.9693x; 3.0017x over previous
//
#include <hip/hip_runtime.h>
#include <hip/hip_bf16.h>
#include <math.h>

#define D_MODEL 768
#define NUM_HEADS 12
#define D_K 64
#define SEQ 2048
#define BATCH 4
#define QKV_N 2304

typedef _Float16 f16;
typedef f16 f16x4 __attribute__((ext_vector_type(4)));
typedef f16 f16x8 __attribute__((ext_vector_type(8)));
typedef float f32x4 __attribute__((ext_vector_type(4)));

// ---------------------------------------------------------------------------
// fp16 MFMA GEMM with fused bias (HW-validated in round 10, unchanged).
// ---------------------------------------------------------------------------
__global__ __launch_bounds__(256) void gemm_mfma_f16(
    const float* __restrict__ A, const float* __restrict__ B,
    const float* __restrict__ bias, float* __restrict__ C,
    int M, int N, int K) {
  const int bm = blockIdx.y * 128;
  const int bn = blockIdx.x * 128;
  const int tid = threadIdx.x;
  const int lane = tid & 63;
  const int wave = tid >> 6;
  const int wr = wave >> 1;
  const int wc = wave & 1;

  __shared__ f16 Als[128][40];
  __shared__ f16 Bls[128][40];

  f32x4 acc[4][4];
#pragma unroll
  for (int i = 0; i < 4; ++i)
#pragma unroll
    for (int j = 0; j < 4; ++j) acc[i][j] = (f32x4){0.f, 0.f, 0.f, 0.f};

  const int frow = lane & 15;
  const int ko   = (lane >> 4) * 8;

  for (int k0 = 0; k0 < K; k0 += 32) {
#pragma unroll
    for (int i = 0; i < 4; ++i) {
      const int f = tid + i * 256;
      const int r = f >> 3;
      const int c4 = (f & 7) * 4;
      const float4 v = *(const float4*)(A + (size_t)(bm + r) * K + k0 + c4);
      f16x4 h = { (f16)v.x, (f16)v.y, (f16)v.z, (f16)v.w };
      *(f16x4*)(&Als[r][c4]) = h;
    }
#pragma unroll
    for (int i = 0; i < 4; ++i) {
      const int f = tid + i * 256;
      const int kr = f >> 5;
      const int nc4 = (f & 31) * 4;
      const float4 v = *(const float4*)(B + (size_t)(k0 + kr) * N + bn + nc4);
      Bls[nc4 + 0][kr] = (f16)v.x;
      Bls[nc4 + 1][kr] = (f16)v.y;
      Bls[nc4 + 2][kr] = (f16)v.z;
      Bls[nc4 + 3][kr] = (f16)v.w;
    }
    __syncthreads();

    f16x8 af[4], bf[4];
#pragma unroll
    for (int mi = 0; mi < 4; ++mi)
      af[mi] = *(const f16x8*)(&Als[wr * 64 + mi * 16 + frow][ko]);
#pragma unroll
    for (int nj = 0; nj < 4; ++nj)
      bf[nj] = *(const f16x8*)(&Bls[wc * 64 + nj * 16 + frow][ko]);

#pragma unroll
    for (int mi = 0; mi < 4; ++mi)
#pragma unroll
      for (int nj = 0; nj < 4; ++nj)
        acc[mi][nj] = __builtin_amdgcn_mfma_f32_16x16x32_f16(
            af[mi], bf[nj], acc[mi][nj], 0, 0, 0);
    __syncthreads();
  }

  const int crow = (lane >> 4) * 4;
  const int ccol = lane & 15;
#pragma unroll
  for (int nj = 0; nj < 4; ++nj) {
    const int col = bn + wc * 64 + nj * 16 + ccol;
    const float bv = bias[col];
#pragma unroll
    for (int mi = 0; mi < 4; ++mi) {
      const int rbase = bm + wr * 64 + mi * 16 + crow;
#pragma unroll
      for (int r = 0; r < 4; ++r) {
        C[(size_t)(rbase + r) * N + col] = acc[mi][nj][r] + bv;
      }
    }
  }
}

// ---------------------------------------------------------------------------
// prep_kv: convert K to f16 [bh][key][d] and V to f16 TRANSPOSED [bh][d][key].
// One block per (b, h, 64-key tile). Memory-bound, runs once.
// ---------------------------------------------------------------------------
__global__ __launch_bounds__(256) void prep_kv(const float* __restrict__ qkv,
                                               f16* __restrict__ Kh,
                                               f16* __restrict__ Vt) {
  const int kt = blockIdx.x, h = blockIdx.y, b = blockIdx.z;
  const int bh = b * NUM_HEADS + h;
  const int t0 = kt * 64;
  const int tid = threadIdx.x;
  __shared__ f16 Vls[64][72];  // [d][key], padded

#pragma unroll
  for (int i = 0; i < 4; ++i) {
    const int slot = tid + i * 256;
    const int row = slot >> 4;        // 0..63 token
    const int c4 = (slot & 15) * 4;   // 0..60 d
    const float* src = qkv + (size_t)(b * SEQ + t0 + row) * QKV_N + h * 192;
    const float4 kv = *(const float4*)(src + 64 + c4);
    f16x4 hk = { (f16)kv.x, (f16)kv.y, (f16)kv.z, (f16)kv.w };
    *(f16x4*)(Kh + ((size_t)bh * SEQ + t0 + row) * 64 + c4) = hk;
    const float4 vv = *(const float4*)(src + 128 + c4);
    Vls[c4 + 0][row] = (f16)vv.x;
    Vls[c4 + 1][row] = (f16)vv.y;
    Vls[c4 + 2][row] = (f16)vv.z;
    Vls[c4 + 3][row] = (f16)vv.w;
  }
  __syncthreads();
#pragma unroll
  for (int i = 0; i < 2; ++i) {
    const int slot = tid + i * 256;
    const int d = slot >> 3;
    const int g8 = (slot & 7) * 8;
    f16x8 hv = *(const f16x8*)(&Vls[d][g8]);
    *(f16x8*)(Vt + ((size_t)bh * 64 + d) * SEQ + t0 + g8) = hv;
  }
}

// ---------------------------------------------------------------------------
// MFMA flash attention. Block = 256 thr (4 waves), 128 q-rows (32 per wave),
// loop over 64-key tiles. Swapped operands: S^T = mfma(K, Q), O^T = mfma(V^T, P^T)
// so every frag read is a row-contiguous ds_read_b128 from XOR-swizzled LDS.
// LDS rows are 64 f16 (128 B); swizzle: unit-offset ^= (row&7)<<3.
// Online softmax per q-row, in-register: 16 in-lane values + shfl_xor 16/32.
// ---------------------------------------------------------------------------
__global__ __launch_bounds__(256) void flash_attn_mfma(
    const float* __restrict__ qkv, const f16* __restrict__ Kh,
    const f16* __restrict__ Vt, float* __restrict__ ctx) {
  const int qt = blockIdx.x, h = blockIdx.y, b = blockIdx.z;
  const int bh = b * NUM_HEADS + h;
  const int q0 = qt * 128;
  const int tid = threadIdx.x;
  const int lane = tid & 63;
  const int w = tid >> 6;
  const int c = lane & 15;
  const int g = lane >> 4;

  __shared__ f16 Ql[128 * 64];
  __shared__ f16 Kl[64 * 64];
  __shared__ f16 Vl[64 * 64];
  __shared__ f16 Pl[4][32 * 64];

  // stage Q once: fp32 -> f16, *0.125 scale folded in, swizzled
#pragma unroll
  for (int i = 0; i < 8; ++i) {
    const int slot = tid + i * 256;
    const int row = slot >> 4;        // 0..127
    const int c4 = (slot & 15) * 4;   // 0..60
    const float4 v = *(const float4*)(
        qkv + (size_t)(b * SEQ + q0 + row) * QKV_N + h * 192 + c4);
    f16x4 hq = { (f16)(v.x * 0.125f), (f16)(v.y * 0.125f),
                 (f16)(v.z * 0.125f), (f16)(v.w * 0.125f) };
    *(f16x4*)(Ql + row * 64 + (c4 ^ ((row & 7) << 3))) = hq;
  }
  __syncthreads();

  // Q B-frags, resident in registers
  f16x8 qf[2][2];  // [nt][s]
#pragma unroll
  for (int nt = 0; nt < 2; ++nt)
#pragma unroll
    for (int s = 0; s < 2; ++s) {
      const int row = w * 32 + nt * 16 + c;
      qf[nt][s] = *(const f16x8*)(Ql + row * 64 +
                                  ((s * 32 + g * 8) ^ ((row & 7) << 3)));
    }

  f32x4 o[4][2];   // [dt][nt], O^T accumulator (d = 16dt+4g+r, q = 16nt+c)
  float m_[2], l_[2];
#pragma unroll
  for (int nt = 0; nt < 2; ++nt) {
    m_[nt] = -INFINITY;
    l_[nt] = 0.f;
#pragma unroll
    for (int dt = 0; dt < 4; ++dt) o[dt][nt] = (f32x4){0.f, 0.f, 0.f, 0.f};
  }

  for (int kt = 0; kt < SEQ / 64; ++kt) {
    // stage K tile [key][d] and V tile [d][key] (both 64x64 f16, swizzled)
#pragma unroll
    for (int i = 0; i < 2; ++i) {
      const int slot = tid + i * 256;
      const int row = slot >> 3;       // 0..63
      const int g8 = (slot & 7) * 8;   // 0..56
      f16x8 hk = *(const f16x8*)(Kh + ((size_t)bh * SEQ + kt * 64 + row) * 64 + g8);
      *(f16x8*)(Kl + row * 64 + (g8 ^ ((row & 7) << 3))) = hk;
      f16x8 hv = *(const f16x8*)(Vt + ((size_t)bh * 64 + row) * SEQ + kt * 64 + g8);
      *(f16x8*)(Vl + row * 64 + (g8 ^ ((row & 7) << 3))) = hv;
    }
    __syncthreads();

    // S^T = K * Q^T : D[key][q], m-tiles over keys, n-tiles over q
    f32x4 s_[4][2];
#pragma unroll
    for (int mt = 0; mt < 4; ++mt)
#pragma unroll
      for (int nt = 0; nt < 2; ++nt) s_[mt][nt] = (f32x4){0.f, 0.f, 0.f, 0.f};

#pragma unroll
    for (int s2 = 0; s2 < 2; ++s2) {
#pragma unroll
      for (int mt = 0; mt < 4; ++mt) {
        const int row = mt * 16 + c;
        const f16x8 kf = *(const f16x8*)(Kl + row * 64 +
                         ((s2 * 32 + g * 8) ^ ((row & 7) << 3)));
#pragma unroll
        for (int nt = 0; nt < 2; ++nt)
          s_[mt][nt] = __builtin_amdgcn_mfma_f32_16x16x32_f16(
              kf, qf[nt][s2], s_[mt][nt], 0, 0, 0);
      }
    }

    // online softmax per q-group; lane holds keys {16mt+4g+r}
#pragma unroll
    for (int nt = 0; nt < 2; ++nt) {
      float tm = -INFINITY;
#pragma unroll
      for (int mt = 0; mt < 4; ++mt)
#pragma unroll
        for (int r = 0; r < 4; ++r) tm = fmaxf(tm, s_[mt][nt][r]);
      tm = fmaxf(tm, __shfl_xor(tm, 16));
      tm = fmaxf(tm, __shfl_xor(tm, 32));
      const float mn = fmaxf(m_[nt], tm);
      const float sc = __expf(m_[nt] - mn);
      m_[nt] = mn;
      float rs = 0.f;
#pragma unroll
      for (int mt = 0; mt < 4; ++mt) {
        f32x4 e;
#pragma unroll
        for (int r = 0; r < 4; ++r) {
          e[r] = __expf(s_[mt][nt][r] - mn);
          rs += e[r];
        }
        s_[mt][nt] = e;
      }
      rs += __shfl_xor(rs, 16);
      rs += __shfl_xor(rs, 32);
      l_[nt] = l_[nt] * sc + rs;
#pragma unroll
      for (int dt = 0; dt < 4; ++dt) o[dt][nt] *= sc;

      // P -> f16, write to per-wave swizzled Pl[q][key]
      const int prow = nt * 16 + c;
#pragma unroll
      for (int mt = 0; mt < 4; ++mt) {
        f16x4 pk = { (f16)s_[mt][nt][0], (f16)s_[mt][nt][1],
                     (f16)s_[mt][nt][2], (f16)s_[mt][nt][3] };
        *(f16x4*)(&Pl[w][prow * 64 +
                         ((mt * 16 + g * 4) ^ ((prow & 7) << 3))]) = pk;
      }
    }

    // O^T += V^T * P^T : D[d][q]
#pragma unroll
    for (int s2 = 0; s2 < 2; ++s2) {
      f16x8 pf[2];
#pragma unroll
      for (int nt = 0; nt < 2; ++nt) {
        const int prow = nt * 16 + c;
        pf[nt] = *(const f16x8*)(&Pl[w][prow * 64 +
                  ((s2 * 32 + g * 8) ^ ((prow & 7) << 3))]);
      }
#pragma unroll
      for (int dt = 0; dt < 4; ++dt) {
        const int row = dt * 16 + c;
        const f16x8 vf = *(const f16x8*)(Vl + row * 64 +
                         ((s2 * 32 + g * 8) ^ ((row & 7) << 3)));
#pragma unroll
        for (int nt = 0; nt < 2; ++nt)
          o[dt][nt] = __builtin_amdgcn_mfma_f32_16x16x32_f16(
              vf, pf[nt], o[dt][nt], 0, 0, 0);
      }
    }
    __syncthreads();
  }

  // epilogue: normalize, write ctx[b, q, h*64 + d] (fp32)
#pragma unroll
  for (int nt = 0; nt < 2; ++nt) {
    const float inv = 1.f / l_[nt];
    const int q = q0 + w * 32 + nt * 16 + c;
#pragma unroll
    for (int dt = 0; dt < 4; ++dt) {
      const float4 r4 = make_float4(o[dt][nt][0] * inv, o[dt][nt][1] * inv,
                                    o[dt][nt][2] * inv, o[dt][nt][3] * inv);
      *(float4*)(ctx + ((size_t)(b * SEQ) + q) * D_MODEL + h * 64 +
                 dt * 16 + g * 4) = r4;
    }
  }
}

// ---------------------------------------------------------------------------
extern "C" void kernel_launch(void* const* d_in, const int* in_sizes, int n_in,
                              void* d_out, int out_size, void* d_ws, size_t ws_size,
                              hipStream_t stream) {
  const float* x     = (const float*)d_in[0];
  const float* W_qkv = (const float*)d_in[1];
  const float* b_qkv = (const float*)d_in[2];
  const float* W_out = (const float*)d_in[3];
  const float* b_out = (const float*)d_in[4];
  float* out = (float*)d_out;

  const int M = BATCH * SEQ;  // 8192

  // workspace layout (bytes): qkv 75.5M | ctx 25.2M | Kh 12.6M | Vt 12.6M
  float* qkv = (float*)d_ws;                           // [8192][2304] f32
  float* ctx = qkv + (size_t)M * QKV_N;                // [8192][768]  f32
  f16* Kh = (f16*)(ctx + (size_t)M * D_MODEL);         // [48][2048][64] f16
  f16* Vt = Kh + (size_t)48 * SEQ * 64;                // [48][64][2048] f16

  dim3 block(256);

  // 1) QKV projection (fp16 MFMA)
  dim3 g1(QKV_N / 128, M / 128);
  hipLaunchKernelGGL(gemm_mfma_f16, g1, block, 0, stream,
                     x, W_qkv, b_qkv, qkv, M, QKV_N, D_MODEL);

  // 2) K/V f16 prep (V transposed per head)
  dim3 g2(SEQ / 64, NUM_HEADS, BATCH);
  hipLaunchKernelGGL(prep_kv, g2, block, 0, stream, qkv, Kh, Vt);

  // 3) MFMA flash attention
  dim3 g3(SEQ / 128, NUM_HEADS, BATCH);
  hipLaunchKernelGGL(flash_attn_mfma, g3, block, 0, stream, qkv, Kh, Vt, ctx);

  // 4) output projection (fp16 MFMA)
  dim3 g4(D_MODEL / 128, M / 128);
  hipLaunchKernelGGL(gemm_mfma_f16, g4, block, 0, stream,
                     ctx, W_out, b_out, out, M, D_MODEL, D_MODEL);
}

// Round 13
// 324.858 us; speedup vs baseline: 35.9917x; 1.0292x over previous
//
#include <hip/hip_runtime.h>
#include <hip/hip_bf16.h>
#include <math.h>

#define D_MODEL 768
#define NUM_HEADS 12
#define D_K 64
#define SEQ 2048
#define BATCH 4
#define QKV_N 2304

typedef _Float16 f16;
typedef f16 f16x4 __attribute__((ext_vector_type(4)));
typedef f16 f16x8 __attribute__((ext_vector_type(8)));
typedef float f32x4 __attribute__((ext_vector_type(4)));

// Bijective XCD swizzle (T1): consecutive M-panel rows land on one XCD's L2.
__device__ inline void xcd_swizzle(int& bx, int& by) {
  const int nx = gridDim.x;
  const int nwg = nx * gridDim.y;
  const int bidlin = blockIdx.y * nx + blockIdx.x;
  const int cpx = nwg >> 3;                      // nwg % 8 == 0 for our grids
  const int wg = (bidlin & 7) * cpx + (bidlin >> 3);
  bx = wg % nx;
  by = wg / nx;
}

// ---------------------------------------------------------------------------
// QKV GEMM, fused epilogue: writes f16 Qh[bh][tok][d] (*0.125), Kh[bh][tok][d],
// Vt[bh][d][tok] directly. 128x128 tile, BK=32, 4 waves. XCD-swizzled.
// ---------------------------------------------------------------------------
__global__ __launch_bounds__(256) void gemm_qkv(
    const float* __restrict__ A, const float* __restrict__ B,
    const float* __restrict__ bias,
    f16* __restrict__ Qh, f16* __restrict__ Kh, f16* __restrict__ Vt,
    int M, int N, int K) {
  int bx, by;
  xcd_swizzle(bx, by);
  const int bm = by * 128;
  const int bn = bx * 128;
  const int tid = threadIdx.x;
  const int lane = tid & 63;
  const int wave = tid >> 6;
  const int wr = wave >> 1;
  const int wc = wave & 1;

  __shared__ f16 Als[128][40];
  __shared__ f16 Bls[128][40];

  f32x4 acc[4][4];
#pragma unroll
  for (int i = 0; i < 4; ++i)
#pragma unroll
    for (int j = 0; j < 4; ++j) acc[i][j] = (f32x4){0.f, 0.f, 0.f, 0.f};

  const int frow = lane & 15;
  const int ko   = (lane >> 4) * 8;

  for (int k0 = 0; k0 < K; k0 += 32) {
#pragma unroll
    for (int i = 0; i < 4; ++i) {
      const int f = tid + i * 256;
      const int r = f >> 3;
      const int c4 = (f & 7) * 4;
      const float4 v = *(const float4*)(A + (size_t)(bm + r) * K + k0 + c4);
      f16x4 h = { (f16)v.x, (f16)v.y, (f16)v.z, (f16)v.w };
      *(f16x4*)(&Als[r][c4]) = h;
    }
#pragma unroll
    for (int i = 0; i < 4; ++i) {
      const int f = tid + i * 256;
      const int kr = f >> 5;
      const int nc4 = (f & 31) * 4;
      const float4 v = *(const float4*)(B + (size_t)(k0 + kr) * N + bn + nc4);
      Bls[nc4 + 0][kr] = (f16)v.x;
      Bls[nc4 + 1][kr] = (f16)v.y;
      Bls[nc4 + 2][kr] = (f16)v.z;
      Bls[nc4 + 3][kr] = (f16)v.w;
    }
    __syncthreads();

    f16x8 af[4], bf[4];
#pragma unroll
    for (int mi = 0; mi < 4; ++mi)
      af[mi] = *(const f16x8*)(&Als[wr * 64 + mi * 16 + frow][ko]);
#pragma unroll
    for (int nj = 0; nj < 4; ++nj)
      bf[nj] = *(const f16x8*)(&Bls[wc * 64 + nj * 16 + frow][ko]);

#pragma unroll
    for (int mi = 0; mi < 4; ++mi)
#pragma unroll
      for (int nj = 0; nj < 4; ++nj)
        acc[mi][nj] = __builtin_amdgcn_mfma_f32_16x16x32_f16(
            af[mi], bf[nj], acc[mi][nj], 0, 0, 0);
    __syncthreads();
  }

  // epilogue: col -> (head, q/k/v, d); rows are tokens.
  const int crow = (lane >> 4) * 4;
  const int ccol = lane & 15;
#pragma unroll
  for (int nj = 0; nj < 4; ++nj) {
    const int col = bn + wc * 64 + nj * 16 + ccol;
    const int h = col / 192;
    const int rem = col - h * 192;
    const int sub = rem >> 6;       // 0=q 1=k 2=v
    const int d = rem & 63;
    const float bv = bias[col];
#pragma unroll
    for (int mi = 0; mi < 4; ++mi) {
      const int tok0 = bm + wr * 64 + mi * 16 + crow;
      const int b = tok0 >> 11;
      const int t0 = tok0 & 2047;
      const int bh = b * NUM_HEADS + h;
      if (sub == 2) {
        f16x4 pv = { (f16)(acc[mi][nj][0] + bv), (f16)(acc[mi][nj][1] + bv),
                     (f16)(acc[mi][nj][2] + bv), (f16)(acc[mi][nj][3] + bv) };
        *(f16x4*)(Vt + ((size_t)bh * 64 + d) * SEQ + t0) = pv;
      } else if (sub == 0) {
#pragma unroll
        for (int r = 0; r < 4; ++r)
          Qh[((size_t)bh * SEQ + t0 + r) * 64 + d] =
              (f16)((acc[mi][nj][r] + bv) * 0.125f);
      } else {
#pragma unroll
        for (int r = 0; r < 4; ++r)
          Kh[((size_t)bh * SEQ + t0 + r) * 64 + d] =
              (f16)(acc[mi][nj][r] + bv);
      }
    }
  }
}

// ---------------------------------------------------------------------------
// fp16 MFMA GEMM with fused bias, fp32 C out (out-proj). XCD-swizzled.
// ---------------------------------------------------------------------------
__global__ __launch_bounds__(256) void gemm_mfma_f16(
    const float* __restrict__ A, const float* __restrict__ B,
    const float* __restrict__ bias, float* __restrict__ C,
    int M, int N, int K) {
  int bx, by;
  xcd_swizzle(bx, by);
  const int bm = by * 128;
  const int bn = bx * 128;
  const int tid = threadIdx.x;
  const int lane = tid & 63;
  const int wave = tid >> 6;
  const int wr = wave >> 1;
  const int wc = wave & 1;

  __shared__ f16 Als[128][40];
  __shared__ f16 Bls[128][40];

  f32x4 acc[4][4];
#pragma unroll
  for (int i = 0; i < 4; ++i)
#pragma unroll
    for (int j = 0; j < 4; ++j) acc[i][j] = (f32x4){0.f, 0.f, 0.f, 0.f};

  const int frow = lane & 15;
  const int ko   = (lane >> 4) * 8;

  for (int k0 = 0; k0 < K; k0 += 32) {
#pragma unroll
    for (int i = 0; i < 4; ++i) {
      const int f = tid + i * 256;
      const int r = f >> 3;
      const int c4 = (f & 7) * 4;
      const float4 v = *(const float4*)(A + (size_t)(bm + r) * K + k0 + c4);
      f16x4 h = { (f16)v.x, (f16)v.y, (f16)v.z, (f16)v.w };
      *(f16x4*)(&Als[r][c4]) = h;
    }
#pragma unroll
    for (int i = 0; i < 4; ++i) {
      const int f = tid + i * 256;
      const int kr = f >> 5;
      const int nc4 = (f & 31) * 4;
      const float4 v = *(const float4*)(B + (size_t)(k0 + kr) * N + bn + nc4);
      Bls[nc4 + 0][kr] = (f16)v.x;
      Bls[nc4 + 1][kr] = (f16)v.y;
      Bls[nc4 + 2][kr] = (f16)v.z;
      Bls[nc4 + 3][kr] = (f16)v.w;
    }
    __syncthreads();

    f16x8 af[4], bf[4];
#pragma unroll
    for (int mi = 0; mi < 4; ++mi)
      af[mi] = *(const f16x8*)(&Als[wr * 64 + mi * 16 + frow][ko]);
#pragma unroll
    for (int nj = 0; nj < 4; ++nj)
      bf[nj] = *(const f16x8*)(&Bls[wc * 64 + nj * 16 + frow][ko]);

#pragma unroll
    for (int mi = 0; mi < 4; ++mi)
#pragma unroll
      for (int nj = 0; nj < 4; ++nj)
        acc[mi][nj] = __builtin_amdgcn_mfma_f32_16x16x32_f16(
            af[mi], bf[nj], acc[mi][nj], 0, 0, 0);
    __syncthreads();
  }

  const int crow = (lane >> 4) * 4;
  const int ccol = lane & 15;
#pragma unroll
  for (int nj = 0; nj < 4; ++nj) {
    const int col = bn + wc * 64 + nj * 16 + ccol;
    const float bv = bias[col];
#pragma unroll
    for (int mi = 0; mi < 4; ++mi) {
      const int rbase = bm + wr * 64 + mi * 16 + crow;
#pragma unroll
      for (int r = 0; r < 4; ++r) {
        C[(size_t)(rbase + r) * N + col] = acc[mi][nj][r] + bv;
      }
    }
  }
}

// ---------------------------------------------------------------------------
// MFMA flash attention (structure validated in round 12). Reads f16 Qh/Kh/Vt.
// ---------------------------------------------------------------------------
__global__ __launch_bounds__(256) void flash_attn_mfma(
    const f16* __restrict__ Qh, const f16* __restrict__ Kh,
    const f16* __restrict__ Vt, float* __restrict__ ctx) {
  const int qt = blockIdx.x, h = blockIdx.y, b = blockIdx.z;
  const int bh = b * NUM_HEADS + h;
  const int q0 = qt * 128;
  const int tid = threadIdx.x;
  const int lane = tid & 63;
  const int w = tid >> 6;
  const int c = lane & 15;
  const int g = lane >> 4;

  __shared__ f16 Ql[128 * 64];
  __shared__ f16 Kl[64 * 64];
  __shared__ f16 Vl[64 * 64];
  __shared__ f16 Pl[4][32 * 64];

  // stage Q (already f16, scaled), swizzled
#pragma unroll
  for (int i = 0; i < 4; ++i) {
    const int slot = tid + i * 256;
    const int row = slot >> 3;       // 0..127
    const int g8 = (slot & 7) * 8;
    f16x8 hq = *(const f16x8*)(Qh + ((size_t)bh * SEQ + q0 + row) * 64 + g8);
    *(f16x8*)(Ql + row * 64 + (g8 ^ ((row & 7) << 3))) = hq;
  }
  __syncthreads();

  f16x8 qf[2][2];  // [nt][s]
#pragma unroll
  for (int nt = 0; nt < 2; ++nt)
#pragma unroll
    for (int s = 0; s < 2; ++s) {
      const int row = w * 32 + nt * 16 + c;
      qf[nt][s] = *(const f16x8*)(Ql + row * 64 +
                                  ((s * 32 + g * 8) ^ ((row & 7) << 3)));
    }

  f32x4 o[4][2];
  float m_[2], l_[2];
#pragma unroll
  for (int nt = 0; nt < 2; ++nt) {
    m_[nt] = -INFINITY;
    l_[nt] = 0.f;
#pragma unroll
    for (int dt = 0; dt < 4; ++dt) o[dt][nt] = (f32x4){0.f, 0.f, 0.f, 0.f};
  }

  for (int kt = 0; kt < SEQ / 64; ++kt) {
#pragma unroll
    for (int i = 0; i < 2; ++i) {
      const int slot = tid + i * 256;
      const int row = slot >> 3;
      const int g8 = (slot & 7) * 8;
      f16x8 hk = *(const f16x8*)(Kh + ((size_t)bh * SEQ + kt * 64 + row) * 64 + g8);
      *(f16x8*)(Kl + row * 64 + (g8 ^ ((row & 7) << 3))) = hk;
      f16x8 hv = *(const f16x8*)(Vt + ((size_t)bh * 64 + row) * SEQ + kt * 64 + g8);
      *(f16x8*)(Vl + row * 64 + (g8 ^ ((row & 7) << 3))) = hv;
    }
    __syncthreads();

    f32x4 s_[4][2];
#pragma unroll
    for (int mt = 0; mt < 4; ++mt)
#pragma unroll
      for (int nt = 0; nt < 2; ++nt) s_[mt][nt] = (f32x4){0.f, 0.f, 0.f, 0.f};

#pragma unroll
    for (int s2 = 0; s2 < 2; ++s2) {
#pragma unroll
      for (int mt = 0; mt < 4; ++mt) {
        const int row = mt * 16 + c;
        const f16x8 kf = *(const f16x8*)(Kl + row * 64 +
                         ((s2 * 32 + g * 8) ^ ((row & 7) << 3)));
#pragma unroll
        for (int nt = 0; nt < 2; ++nt)
          s_[mt][nt] = __builtin_amdgcn_mfma_f32_16x16x32_f16(
              kf, qf[nt][s2], s_[mt][nt], 0, 0, 0);
      }
    }

#pragma unroll
    for (int nt = 0; nt < 2; ++nt) {
      float tm = -INFINITY;
#pragma unroll
      for (int mt = 0; mt < 4; ++mt)
#pragma unroll
        for (int r = 0; r < 4; ++r) tm = fmaxf(tm, s_[mt][nt][r]);
      tm = fmaxf(tm, __shfl_xor(tm, 16));
      tm = fmaxf(tm, __shfl_xor(tm, 32));
      const float mn = fmaxf(m_[nt], tm);
      const float sc = __expf(m_[nt] - mn);
      m_[nt] = mn;
      float rs = 0.f;
#pragma unroll
      for (int mt = 0; mt < 4; ++mt) {
        f32x4 e;
#pragma unroll
        for (int r = 0; r < 4; ++r) {
          e[r] = __expf(s_[mt][nt][r] - mn);
          rs += e[r];
        }
        s_[mt][nt] = e;
      }
      rs += __shfl_xor(rs, 16);
      rs += __shfl_xor(rs, 32);
      l_[nt] = l_[nt] * sc + rs;
#pragma unroll
      for (int dt = 0; dt < 4; ++dt) o[dt][nt] *= sc;

      const int prow = nt * 16 + c;
#pragma unroll
      for (int mt = 0; mt < 4; ++mt) {
        f16x4 pk = { (f16)s_[mt][nt][0], (f16)s_[mt][nt][1],
                     (f16)s_[mt][nt][2], (f16)s_[mt][nt][3] };
        *(f16x4*)(&Pl[w][prow * 64 +
                         ((mt * 16 + g * 4) ^ ((prow & 7) << 3))]) = pk;
      }
    }

#pragma unroll
    for (int s2 = 0; s2 < 2; ++s2) {
      f16x8 pf[2];
#pragma unroll
      for (int nt = 0; nt < 2; ++nt) {
        const int prow = nt * 16 + c;
        pf[nt] = *(const f16x8*)(&Pl[w][prow * 64 +
                  ((s2 * 32 + g * 8) ^ ((prow & 7) << 3))]);
      }
#pragma unroll
      for (int dt = 0; dt < 4; ++dt) {
        const int row = dt * 16 + c;
        const f16x8 vf = *(const f16x8*)(Vl + row * 64 +
                         ((s2 * 32 + g * 8) ^ ((row & 7) << 3)));
#pragma unroll
        for (int nt = 0; nt < 2; ++nt)
          o[dt][nt] = __builtin_amdgcn_mfma_f32_16x16x32_f16(
              vf, pf[nt], o[dt][nt], 0, 0, 0);
      }
    }
    __syncthreads();
  }

#pragma unroll
  for (int nt = 0; nt < 2; ++nt) {
    const float inv = 1.f / l_[nt];
    const int q = q0 + w * 32 + nt * 16 + c;
#pragma unroll
    for (int dt = 0; dt < 4; ++dt) {
      const float4 r4 = make_float4(o[dt][nt][0] * inv, o[dt][nt][1] * inv,
                                    o[dt][nt][2] * inv, o[dt][nt][3] * inv);
      *(float4*)(ctx + ((size_t)(b * SEQ) + q) * D_MODEL + h * 64 +
                 dt * 16 + g * 4) = r4;
    }
  }
}

// ---------------------------------------------------------------------------
extern "C" void kernel_launch(void* const* d_in, const int* in_sizes, int n_in,
                              void* d_out, int out_size, void* d_ws, size_t ws_size,
                              hipStream_t stream) {
  const float* x     = (const float*)d_in[0];
  const float* W_qkv = (const float*)d_in[1];
  const float* b_qkv = (const float*)d_in[2];
  const float* W_out = (const float*)d_in[3];
  const float* b_out = (const float*)d_in[4];
  float* out = (float*)d_out;

  const int M = BATCH * SEQ;  // 8192
  const int BH = BATCH * NUM_HEADS;  // 48

  // workspace: ctx f32 25.2M | Qh 12.6M | Kh 12.6M | Vt 12.6M
  float* ctx = (float*)d_ws;                       // [8192][768] f32
  f16* Qh = (f16*)(ctx + (size_t)M * D_MODEL);     // [48][2048][64]
  f16* Kh = Qh + (size_t)BH * SEQ * 64;            // [48][2048][64]
  f16* Vt = Kh + (size_t)BH * SEQ * 64;            // [48][64][2048]

  dim3 block(256);

  // 1) QKV projection, fused f16 Q/K/V^T write (no fp32 qkv intermediate)
  dim3 g1(QKV_N / 128, M / 128);                   // (18, 64) = 1152 blocks
  hipLaunchKernelGGL(gemm_qkv, g1, block, 0, stream,
                     x, W_qkv, b_qkv, Qh, Kh, Vt, M, QKV_N, D_MODEL);

  // 2) MFMA flash attention
  dim3 g3(SEQ / 128, NUM_HEADS, BATCH);
  hipLaunchKernelGGL(flash_attn_mfma, g3, block, 0, stream, Qh, Kh, Vt, ctx);

  // 3) output projection
  dim3 g4(D_MODEL / 128, M / 128);                 // (6, 64) = 384 blocks
  hipLaunchKernelGGL(gemm_mfma_f16, g4, block, 0, stream,
                     ctx, W_out, b_out, out, M, D_MODEL, D_MODEL);
}

// Round 14
// 188.594 us; speedup vs baseline: 61.9968x; 1.7225x over previous
//
#include <hip/hip_runtime.h>
#include <hip/hip_bf16.h>
#include <math.h>

#define D_MODEL 768
#define NUM_HEADS 12
#define D_K 64
#define SEQ 2048
#define BATCH 4
#define QKV_N 2304

typedef _Float16 f16;
typedef f16 f16x4 __attribute__((ext_vector_type(4)));
typedef f16 f16x8 __attribute__((ext_vector_type(8)));
typedef float f32x4 __attribute__((ext_vector_type(4)));

// async global->LDS, 16 B per lane; LDS dest must be wave-uniform base.
__device__ __forceinline__ void gload_lds16(const f16* g, f16* l) {
  __builtin_amdgcn_global_load_lds(
      (const __attribute__((address_space(1))) void*)g,
      (__attribute__((address_space(3))) void*)l, 16, 0, 0);
}

// Bijective XCD swizzle (T1).
__device__ inline void xcd_swizzle(int& bx, int& by) {
  const int nx = gridDim.x;
  const int nwg = nx * gridDim.y;
  const int bidlin = blockIdx.y * nx + blockIdx.x;
  const int cpx = nwg >> 3;  // nwg % 8 == 0 for our grids
  const int wg = (bidlin & 7) * cpx + (bidlin >> 3);
  bx = wg % nx;
  by = wg / nx;
}

// ---------------------------------------------------------------------------
// prep_x: fp32 -> f16 elementwise. 6291456 elems, 8/thread-iter, 2 iters.
// ---------------------------------------------------------------------------
__global__ __launch_bounds__(256) void prep_x(const float* __restrict__ x,
                                              f16* __restrict__ xh) {
  const int idx = blockIdx.x * 256 + threadIdx.x;  // 0..393215
#pragma unroll
  for (int i = 0; i < 2; ++i) {
    const size_t c = (size_t)idx + (size_t)i * 393216;
    const float4 a = *(const float4*)(x + c * 8);
    const float4 b = *(const float4*)(x + c * 8 + 4);
    f16x8 h = { (f16)a.x, (f16)a.y, (f16)a.z, (f16)a.w,
                (f16)b.x, (f16)b.y, (f16)b.z, (f16)b.w };
    *(f16x8*)(xh + c * 8) = h;
  }
}

// ---------------------------------------------------------------------------
// prep_wt: W[K][N] fp32 -> Wt[N][K] f16 (transpose + convert). 64x64 tiles.
// ---------------------------------------------------------------------------
__global__ __launch_bounds__(256) void prep_wt(const float* __restrict__ W,
                                               f16* __restrict__ Wt,
                                               int K, int N) {
  const int n0 = blockIdx.x * 64;
  const int k0 = blockIdx.y * 64;
  const int tid = threadIdx.x;
  __shared__ f16 t[64][72];  // [n][k], padded

#pragma unroll
  for (int i = 0; i < 4; ++i) {
    const int slot = tid + i * 256;
    const int r = slot >> 4;          // k-row 0..63
    const int c4 = (slot & 15) * 4;   // n-col 0..60
    const float4 v = *(const float4*)(W + (size_t)(k0 + r) * N + n0 + c4);
    t[c4 + 0][r] = (f16)v.x;
    t[c4 + 1][r] = (f16)v.y;
    t[c4 + 2][r] = (f16)v.z;
    t[c4 + 3][r] = (f16)v.w;
  }
  __syncthreads();
#pragma unroll
  for (int i = 0; i < 2; ++i) {
    const int slot = tid + i * 256;
    const int n = slot >> 3;          // 0..63
    const int kc = (slot & 7) * 8;    // 0..56
    *(f16x8*)(Wt + (size_t)(n0 + n) * K + k0 + kc) = *(const f16x8*)(&t[n][kc]);
  }
}

// ---------------------------------------------------------------------------
// Core MFMA GEMM loop (f16 A [M][K], f16 B [N][K], both row-major-in-k),
// 128x128 tile, BK=32, 4 waves (2x2), global_load_lds staging, linear LDS
// [row][32] f16 (64-B rows -> bank-balanced b128 reads).
// ---------------------------------------------------------------------------
#define GEMM_CORE(A_, B_, K_)                                               \
  __shared__ f16 Als[128 * 32];                                             \
  __shared__ f16 Bls[128 * 32];                                             \
  f32x4 acc[4][4];                                                          \
  _Pragma("unroll") for (int i = 0; i < 4; ++i)                             \
      _Pragma("unroll") for (int j = 0; j < 4; ++j)                         \
          acc[i][j] = (f32x4){0.f, 0.f, 0.f, 0.f};                          \
  const int sr = w * 32 + (lane >> 2);                                      \
  const int sc = (lane & 3) * 8;                                            \
  const f16* gA0 = A_ + (size_t)(bm + sr) * K_ + sc;                        \
  const f16* gA1 = gA0 + (size_t)16 * K_;                                   \
  const f16* gB0 = B_ + (size_t)(bn + sr) * K_ + sc;                        \
  const f16* gB1 = gB0 + (size_t)16 * K_;                                   \
  f16* lA0 = Als + (w * 32) * 32;                                           \
  f16* lA1 = lA0 + 16 * 32;                                                 \
  f16* lB0 = Bls + (w * 32) * 32;                                           \
  f16* lB1 = lB0 + 16 * 32;                                                 \
  for (int k0 = 0; k0 < K_; k0 += 32) {                                     \
    gload_lds16(gA0 + k0, lA0);                                             \
    gload_lds16(gA1 + k0, lA1);                                             \
    gload_lds16(gB0 + k0, lB0);                                             \
    gload_lds16(gB1 + k0, lB1);                                             \
    __syncthreads();                                                        \
    f16x8 af[4], bf[4];                                                     \
    _Pragma("unroll") for (int mi = 0; mi < 4; ++mi)                        \
        af[mi] = *(const f16x8*)(Als + (wr * 64 + mi * 16 + c) * 32 + g * 8); \
    _Pragma("unroll") for (int nj = 0; nj < 4; ++nj)                        \
        bf[nj] = *(const f16x8*)(Bls + (wc * 64 + nj * 16 + c) * 32 + g * 8); \
    _Pragma("unroll") for (int mi = 0; mi < 4; ++mi)                        \
        _Pragma("unroll") for (int nj = 0; nj < 4; ++nj)                    \
            acc[mi][nj] = __builtin_amdgcn_mfma_f32_16x16x32_f16(           \
                af[mi], bf[nj], acc[mi][nj], 0, 0, 0);                      \
    __syncthreads();                                                        \
  }

// ---------------------------------------------------------------------------
// QKV GEMM: A=xh f16, B=Wqt f16 [2304][768]; scatter epilogue -> Qh/Kh/Vt.
// ---------------------------------------------------------------------------
__global__ __launch_bounds__(256) void gemm_qkv(
    const f16* __restrict__ A, const f16* __restrict__ B,
    const float* __restrict__ bias,
    f16* __restrict__ Qh, f16* __restrict__ Kh, f16* __restrict__ Vt) {
  int bx, by;
  xcd_swizzle(bx, by);
  const int bm = by * 128;
  const int bn = bx * 128;
  const int tid = threadIdx.x;
  const int lane = tid & 63;
  const int w = tid >> 6;
  const int wr = w >> 1;
  const int wc = w & 1;
  const int c = lane & 15;
  const int g = lane >> 4;

  GEMM_CORE(A, B, 768)

  // epilogue: col -> (head, q/k/v, d); rows are tokens. (validated r13)
  const int crow = g * 4;
  const int ccol = c;
#pragma unroll
  for (int nj = 0; nj < 4; ++nj) {
    const int col = bn + wc * 64 + nj * 16 + ccol;
    const int h = col / 192;
    const int rem = col - h * 192;
    const int sub = rem >> 6;  // 0=q 1=k 2=v
    const int d = rem & 63;
    const float bv = bias[col];
#pragma unroll
    for (int mi = 0; mi < 4; ++mi) {
      const int tok0 = bm + wr * 64 + mi * 16 + crow;
      const int b = tok0 >> 11;
      const int t0 = tok0 & 2047;
      const int bh = b * NUM_HEADS + h;
      if (sub == 2) {
        f16x4 pv = { (f16)(acc[mi][nj][0] + bv), (f16)(acc[mi][nj][1] + bv),
                     (f16)(acc[mi][nj][2] + bv), (f16)(acc[mi][nj][3] + bv) };
        *(f16x4*)(Vt + ((size_t)bh * 64 + d) * SEQ + t0) = pv;
      } else if (sub == 0) {
#pragma unroll
        for (int r = 0; r < 4; ++r)
          Qh[((size_t)bh * SEQ + t0 + r) * 64 + d] =
              (f16)((acc[mi][nj][r] + bv) * 0.125f);
      } else {
#pragma unroll
        for (int r = 0; r < 4; ++r)
          Kh[((size_t)bh * SEQ + t0 + r) * 64 + d] =
              (f16)(acc[mi][nj][r] + bv);
      }
    }
  }
}

// ---------------------------------------------------------------------------
// Out-proj GEMM: A=ctxh f16 [8192][768], B=Wot f16 [768][768]; fp32 C + bias.
// ---------------------------------------------------------------------------
__global__ __launch_bounds__(256) void gemm_out(
    const f16* __restrict__ A, const f16* __restrict__ B,
    const float* __restrict__ bias, float* __restrict__ C) {
  int bx, by;
  xcd_swizzle(bx, by);
  const int bm = by * 128;
  const int bn = bx * 128;
  const int tid = threadIdx.x;
  const int lane = tid & 63;
  const int w = tid >> 6;
  const int wr = w >> 1;
  const int wc = w & 1;
  const int c = lane & 15;
  const int g = lane >> 4;

  GEMM_CORE(A, B, 768)

  const int crow = g * 4;
  const int ccol = c;
#pragma unroll
  for (int nj = 0; nj < 4; ++nj) {
    const int col = bn + wc * 64 + nj * 16 + ccol;
    const float bv = bias[col];
#pragma unroll
    for (int mi = 0; mi < 4; ++mi) {
      const int rbase = bm + wr * 64 + mi * 16 + crow;
#pragma unroll
      for (int r = 0; r < 4; ++r) {
        C[(size_t)(rbase + r) * D_MODEL + col] = acc[mi][nj][r] + bv;
      }
    }
  }
}

// ---------------------------------------------------------------------------
// MFMA flash attention (validated r12/r13). Epilogue now writes f16 ctx.
// ---------------------------------------------------------------------------
__global__ __launch_bounds__(256) void flash_attn_mfma(
    const f16* __restrict__ Qh, const f16* __restrict__ Kh,
    const f16* __restrict__ Vt, f16* __restrict__ ctxh) {
  const int qt = blockIdx.x, h = blockIdx.y, b = blockIdx.z;
  const int bh = b * NUM_HEADS + h;
  const int q0 = qt * 128;
  const int tid = threadIdx.x;
  const int lane = tid & 63;
  const int w = tid >> 6;
  const int c = lane & 15;
  const int g = lane >> 4;

  __shared__ f16 Ql[128 * 64];
  __shared__ f16 Kl[64 * 64];
  __shared__ f16 Vl[64 * 64];
  __shared__ f16 Pl[4][32 * 64];

#pragma unroll
  for (int i = 0; i < 4; ++i) {
    const int slot = tid + i * 256;
    const int row = slot >> 3;
    const int g8 = (slot & 7) * 8;
    f16x8 hq = *(const f16x8*)(Qh + ((size_t)bh * SEQ + q0 + row) * 64 + g8);
    *(f16x8*)(Ql + row * 64 + (g8 ^ ((row & 7) << 3))) = hq;
  }
  __syncthreads();

  f16x8 qf[2][2];
#pragma unroll
  for (int nt = 0; nt < 2; ++nt)
#pragma unroll
    for (int s = 0; s < 2; ++s) {
      const int row = w * 32 + nt * 16 + c;
      qf[nt][s] = *(const f16x8*)(Ql + row * 64 +
                                  ((s * 32 + g * 8) ^ ((row & 7) << 3)));
    }

  f32x4 o[4][2];
  float m_[2], l_[2];
#pragma unroll
  for (int nt = 0; nt < 2; ++nt) {
    m_[nt] = -INFINITY;
    l_[nt] = 0.f;
#pragma unroll
    for (int dt = 0; dt < 4; ++dt) o[dt][nt] = (f32x4){0.f, 0.f, 0.f, 0.f};
  }

  for (int kt = 0; kt < SEQ / 64; ++kt) {
#pragma unroll
    for (int i = 0; i < 2; ++i) {
      const int slot = tid + i * 256;
      const int row = slot >> 3;
      const int g8 = (slot & 7) * 8;
      f16x8 hk = *(const f16x8*)(Kh + ((size_t)bh * SEQ + kt * 64 + row) * 64 + g8);
      *(f16x8*)(Kl + row * 64 + (g8 ^ ((row & 7) << 3))) = hk;
      f16x8 hv = *(const f16x8*)(Vt + ((size_t)bh * 64 + row) * SEQ + kt * 64 + g8);
      *(f16x8*)(Vl + row * 64 + (g8 ^ ((row & 7) << 3))) = hv;
    }
    __syncthreads();

    f32x4 s_[4][2];
#pragma unroll
    for (int mt = 0; mt < 4; ++mt)
#pragma unroll
      for (int nt = 0; nt < 2; ++nt) s_[mt][nt] = (f32x4){0.f, 0.f, 0.f, 0.f};

#pragma unroll
    for (int s2 = 0; s2 < 2; ++s2) {
#pragma unroll
      for (int mt = 0; mt < 4; ++mt) {
        const int row = mt * 16 + c;
        const f16x8 kf = *(const f16x8*)(Kl + row * 64 +
                         ((s2 * 32 + g * 8) ^ ((row & 7) << 3)));
#pragma unroll
        for (int nt = 0; nt < 2; ++nt)
          s_[mt][nt] = __builtin_amdgcn_mfma_f32_16x16x32_f16(
              kf, qf[nt][s2], s_[mt][nt], 0, 0, 0);
      }
    }

#pragma unroll
    for (int nt = 0; nt < 2; ++nt) {
      float tm = -INFINITY;
#pragma unroll
      for (int mt = 0; mt < 4; ++mt)
#pragma unroll
        for (int r = 0; r < 4; ++r) tm = fmaxf(tm, s_[mt][nt][r]);
      tm = fmaxf(tm, __shfl_xor(tm, 16));
      tm = fmaxf(tm, __shfl_xor(tm, 32));
      const float mn = fmaxf(m_[nt], tm);
      const float sc = __expf(m_[nt] - mn);
      m_[nt] = mn;
      float rs = 0.f;
#pragma unroll
      for (int mt = 0; mt < 4; ++mt) {
        f32x4 e;
#pragma unroll
        for (int r = 0; r < 4; ++r) {
          e[r] = __expf(s_[mt][nt][r] - mn);
          rs += e[r];
        }
        s_[mt][nt] = e;
      }
      rs += __shfl_xor(rs, 16);
      rs += __shfl_xor(rs, 32);
      l_[nt] = l_[nt] * sc + rs;
#pragma unroll
      for (int dt = 0; dt < 4; ++dt) o[dt][nt] *= sc;

      const int prow = nt * 16 + c;
#pragma unroll
      for (int mt = 0; mt < 4; ++mt) {
        f16x4 pk = { (f16)s_[mt][nt][0], (f16)s_[mt][nt][1],
                     (f16)s_[mt][nt][2], (f16)s_[mt][nt][3] };
        *(f16x4*)(&Pl[w][prow * 64 +
                         ((mt * 16 + g * 4) ^ ((prow & 7) << 3))]) = pk;
      }
    }

#pragma unroll
    for (int s2 = 0; s2 < 2; ++s2) {
      f16x8 pf[2];
#pragma unroll
      for (int nt = 0; nt < 2; ++nt) {
        const int prow = nt * 16 + c;
        pf[nt] = *(const f16x8*)(&Pl[w][prow * 64 +
                  ((s2 * 32 + g * 8) ^ ((prow & 7) << 3))]);
      }
#pragma unroll
      for (int dt = 0; dt < 4; ++dt) {
        const int row = dt * 16 + c;
        const f16x8 vf = *(const f16x8*)(Vl + row * 64 +
                         ((s2 * 32 + g * 8) ^ ((row & 7) << 3)));
#pragma unroll
        for (int nt = 0; nt < 2; ++nt)
          o[dt][nt] = __builtin_amdgcn_mfma_f32_16x16x32_f16(
              vf, pf[nt], o[dt][nt], 0, 0, 0);
      }
    }
    __syncthreads();
  }

#pragma unroll
  for (int nt = 0; nt < 2; ++nt) {
    const float inv = 1.f / l_[nt];
    const int q = q0 + w * 32 + nt * 16 + c;
#pragma unroll
    for (int dt = 0; dt < 4; ++dt) {
      f16x4 r4 = { (f16)(o[dt][nt][0] * inv), (f16)(o[dt][nt][1] * inv),
                   (f16)(o[dt][nt][2] * inv), (f16)(o[dt][nt][3] * inv) };
      *(f16x4*)(ctxh + ((size_t)(b * SEQ) + q) * D_MODEL + h * 64 +
                dt * 16 + g * 4) = r4;
    }
  }
}

// ---------------------------------------------------------------------------
extern "C" void kernel_launch(void* const* d_in, const int* in_sizes, int n_in,
                              void* d_out, int out_size, void* d_ws, size_t ws_size,
                              hipStream_t stream) {
  const float* x     = (const float*)d_in[0];
  const float* W_qkv = (const float*)d_in[1];
  const float* b_qkv = (const float*)d_in[2];
  const float* W_out = (const float*)d_in[3];
  const float* b_out = (const float*)d_in[4];
  float* out = (float*)d_out;

  const int M = BATCH * SEQ;          // 8192
  const int BH = BATCH * NUM_HEADS;   // 48

  // workspace (f16 elems): xh 6.3M | Wqt 1.77M | Wot 0.59M | Qh/Kh/Vt 6.3M ea
  // | ctxh 6.3M   -> ~68 MB total
  f16* xh   = (f16*)d_ws;                          // [8192][768]
  f16* Wqt  = xh + (size_t)M * D_MODEL;            // [2304][768]
  f16* Wot  = Wqt + (size_t)QKV_N * D_MODEL;       // [768][768]
  f16* Qh   = Wot + (size_t)D_MODEL * D_MODEL;     // [48][2048][64]
  f16* Kh   = Qh + (size_t)BH * SEQ * 64;
  f16* Vt   = Kh + (size_t)BH * SEQ * 64;          // [48][64][2048]
  f16* ctxh = Vt + (size_t)BH * SEQ * 64;          // [8192][768]

  dim3 block(256);

  // 0) one-shot conversions
  hipLaunchKernelGGL(prep_x, dim3(1536), block, 0, stream, x, xh);
  hipLaunchKernelGGL(prep_wt, dim3(QKV_N / 64, D_MODEL / 64), block, 0, stream,
                     W_qkv, Wqt, D_MODEL, QKV_N);
  hipLaunchKernelGGL(prep_wt, dim3(D_MODEL / 64, D_MODEL / 64), block, 0, stream,
                     W_out, Wot, D_MODEL, D_MODEL);

  // 1) QKV projection (gload_lds staging, fused f16 Q/K/V^T epilogue)
  hipLaunchKernelGGL(gemm_qkv, dim3(QKV_N / 128, M / 128), block, 0, stream,
                     xh, Wqt, b_qkv, Qh, Kh, Vt);

  // 2) MFMA flash attention (writes f16 ctx)
  hipLaunchKernelGGL(flash_attn_mfma, dim3(SEQ / 128, NUM_HEADS, BATCH), block,
                     0, stream, Qh, Kh, Vt, ctxh);

  // 3) output projection
  hipLaunchKernelGGL(gemm_out, dim3(D_MODEL / 128, M / 128), block, 0, stream,
                     ctxh, Wot, b_out, out);
}